// Round 3
// baseline (187.412 us; speedup 1.0000x reference)
//
#include <hip/hip_runtime.h>

// Discriminator: the reference's attention matmul is DEAD (del attn) and
// hidden_in rows 1..5 are identical (node 0 repeated TOPK=5 times).
// Only node_vec[:,0,:] ("first") and node_vec[:,-1,:] ("last") are needed.
// One block per batch element (grid 256 = #CUs); 512 threads (2 waves/SIMD)
// with split-K + float4 weight loads on the long-K stages.
// Stage-2 K-splits are 16B-aligned (7x96 + 1x80) so activation reads are
// ds_read_b128 instead of scalar ds_read_b32.

#define BATCH     256
#define NN        200
#define MM        200
#define EMB_DIM   16
#define LSTM_DIM  512
#define NODE_DIM  752   // 2*8 + 14*16 + 512

__global__ __launch_bounds__(512) void disc_kernel(
    const float* __restrict__ lstm,      // (B, M, 1, 512)
    const int*   __restrict__ trees,     // (B, N, 17)
    const float* __restrict__ emb,       // (200, 16)
    const float* __restrict__ node_w1,   // (752, 128)
    const float* __restrict__ node_b1,   // (128)
    const float* __restrict__ node_w2,   // (128, 32)
    const float* __restrict__ node_b2,   // (32)
    const float* __restrict__ ta_w1,     // (192, 128)
    const float* __restrict__ ta_b1,     // (128)
    const float* __restrict__ ta_w2,     // (128, 32)
    const float* __restrict__ ta_b2,     // (32)
    const float* __restrict__ ff_w1,     // (32, 64)
    const float* __restrict__ ff_b1,     // (64)
    const float* __restrict__ ff_w2,     // (64, 32)
    const float* __restrict__ ff_b2,     // (32)
    const float* __restrict__ ts_w,      // (32, 1)
    const float* __restrict__ ts_b,      // (1)
    float*       __restrict__ out)       // (B, 1)
{
    const int b = blockIdx.x;
    const int t = threadIdx.x;

    __shared__ __align__(16) float node[2][NODE_DIM]; // row 0 = last (node 199), row 1 = first (node 0)
    __shared__ __align__(16) float part2[2][8][128];  // stage-2 split-K partials
    __shared__ __align__(16) float part4[16][128];    // stage-4 split-K partials
    __shared__ float part3[2][8][32];
    __shared__ float part5[16][32];
    __shared__ float part6[8][64];
    __shared__ float part7[16][32];
    __shared__ float y1[2][128];
    __shared__ float h192[192];
    __shared__ float t1s[128];
    __shared__ float t2s[32];
    __shared__ float f1s[64];
    __shared__ float f2s[32];

    // ---- gather: node[r] = [pe(tr0)|pe(tr1) : 16][emb(tr[2..15]) : 224][lstm[tr16] : 512]
    {
        if (t < 256) {
            // lstm section: 2 rows x 128 float4
            const int r = t >> 7, q = t & 127;
            const int* tr = trees + (b * NN + (r ? 0 : NN - 1)) * 17;
            const int m = tr[16];
            const float4 v = *reinterpret_cast<const float4*>(
                lstm + ((size_t)b * MM + m) * LSTM_DIM + q * 4);
            *reinterpret_cast<float4*>(&node[r][240 + q * 4]) = v;
        } else if (t < 368) {
            // emb section: 2 rows x 14 idx x 4 float4
            const int idx = t - 256;            // 0..111
            const int r = idx / 56, rem = idx % 56;
            const int j = rem >> 2, c4 = rem & 3;
            const int* tr = trees + (b * NN + (r ? 0 : NN - 1)) * 17;
            const float4 v = *reinterpret_cast<const float4*>(
                emb + tr[2 + j] * EMB_DIM + c4 * 4);
            *reinterpret_cast<float4*>(&node[r][16 + j * 16 + c4 * 4]) = v;
        } else if (t < 400) {
            // positional encoding: 2 rows x 16, double precision (matches numpy>=2 f64 path;
            // diff vs f32 path is a few ULP — inside any sane tolerance either way)
            const int idx = t - 368;            // 0..31
            const int r = idx >> 4, d = idx & 15;
            const int* tr = trees + (b * NN + (r ? 0 : NN - 1)) * 17;
            const int p  = (d < 8) ? tr[0] : tr[1];
            const int dd = d & 7;
            const int k  = dd >> 1;
            const double div = exp((double)(2 * k) * -1.1512925464970228);  // -ln(10000)/8
            const double arg = (double)p * div;
            node[r][d] = (float)((dd & 1) ? cos(arg) : sin(arg));
        }
    }
    __syncthreads();

    // ---- stage 2: y1[row] = relu(node[row] @ node_w1 + b1)  (2x752x128)
    // 512 thr = row(2) x ksplit(8, 16B-aligned: 7x96+1x80) x ogroup(32 x 4 outs)
    {
        const int row = t >> 8;
        const int ks  = (t >> 5) & 7;
        const int og  = t & 31;
        const float4* __restrict__ x4p = reinterpret_cast<const float4*>(node[row]);
        const float* __restrict__ w = node_w1 + og * 4;
        float a0 = 0.f, a1 = 0.f, a2 = 0.f, a3 = 0.f;
        const int k40 = ks * 24;                       // 96/4 float4s per split
        const int k4e = (ks == 7) ? 188 : k40 + 24;    // 752/4 = 188 total
        #pragma unroll 2
        for (int k4 = k40; k4 < k4e; ++k4) {
            const float4 x4 = x4p[k4];
            const int kb = k4 * 4;
            const float4 w0 = *reinterpret_cast<const float4*>(w + (kb + 0) * 128);
            const float4 w1 = *reinterpret_cast<const float4*>(w + (kb + 1) * 128);
            const float4 w2 = *reinterpret_cast<const float4*>(w + (kb + 2) * 128);
            const float4 w3 = *reinterpret_cast<const float4*>(w + (kb + 3) * 128);
            a0 = fmaf(x4.x, w0.x, a0); a1 = fmaf(x4.x, w0.y, a1);
            a2 = fmaf(x4.x, w0.z, a2); a3 = fmaf(x4.x, w0.w, a3);
            a0 = fmaf(x4.y, w1.x, a0); a1 = fmaf(x4.y, w1.y, a1);
            a2 = fmaf(x4.y, w1.z, a2); a3 = fmaf(x4.y, w1.w, a3);
            a0 = fmaf(x4.z, w2.x, a0); a1 = fmaf(x4.z, w2.y, a1);
            a2 = fmaf(x4.z, w2.z, a2); a3 = fmaf(x4.z, w2.w, a3);
            a0 = fmaf(x4.w, w3.x, a0); a1 = fmaf(x4.w, w3.y, a1);
            a2 = fmaf(x4.w, w3.z, a2); a3 = fmaf(x4.w, w3.w, a3);
        }
        *reinterpret_cast<float4*>(&part2[row][ks][og * 4]) = make_float4(a0, a1, a2, a3);
    }
    __syncthreads();
    if (t < 256) {
        const int row = t >> 7, o = t & 127;
        float a = 0.f;
        #pragma unroll
        for (int ks = 0; ks < 8; ++ks) a += part2[row][ks][o];
        y1[row][o] = fmaxf(a + node_b1[o], 0.f);
    }
    __syncthreads();

    // ---- stage 3: h[row] = relu(y1[row] @ node_w2 + b2)  (2x128x32); h192 = [h_last, h_first x5]
    {
        const int row = t >> 8;
        const int ks  = (t >> 5) & 7;   // 8 splits of 16
        const int o   = t & 31;
        float a = 0.f;
        const int k0 = ks * 16;
        #pragma unroll
        for (int k = k0; k < k0 + 16; ++k)
            a = fmaf(y1[row][k], node_w2[k * 32 + o], a);
        part3[row][ks][o] = a;
    }
    __syncthreads();
    if (t < 64) {
        const int row = t >> 5, o = t & 31;
        float a = 0.f;
        #pragma unroll
        for (int ks = 0; ks < 8; ++ks) a += part3[row][ks][o];
        const float h = fmaxf(a + node_b2[o], 0.f);
        if (row == 0) {
            h192[o] = h;
        } else {
            #pragma unroll
            for (int rep = 0; rep < 5; ++rep) h192[32 + 32 * rep + o] = h;
        }
    }
    __syncthreads();

    // ---- stage 4: t1 = relu(h192 @ ta_w1 + b)  (192x128); ksplit(16 x 12) x ogroup(32 x 4)
    {
        const int ks = t >> 5;
        const int og = t & 31;
        const float* __restrict__ w = ta_w1 + og * 4;
        float a0 = 0.f, a1 = 0.f, a2 = 0.f, a3 = 0.f;
        const int k0 = ks * 12;
        #pragma unroll
        for (int k = k0; k < k0 + 12; ++k) {
            const float4 w4 = *reinterpret_cast<const float4*>(w + k * 128);
            const float xv = h192[k];
            a0 = fmaf(xv, w4.x, a0);
            a1 = fmaf(xv, w4.y, a1);
            a2 = fmaf(xv, w4.z, a2);
            a3 = fmaf(xv, w4.w, a3);
        }
        *reinterpret_cast<float4*>(&part4[ks][og * 4]) = make_float4(a0, a1, a2, a3);
    }
    __syncthreads();
    if (t < 128) {
        float a = 0.f;
        #pragma unroll
        for (int ks = 0; ks < 16; ++ks) a += part4[ks][t];
        t1s[t] = fmaxf(a + ta_b1[t], 0.f);
    }
    __syncthreads();

    // ---- stage 5: t2 = relu(t1 @ ta_w2 + b)  (128x32); 16 splits of 8
    {
        const int ks = t >> 5;
        const int o  = t & 31;
        float a = 0.f;
        const int k0 = ks * 8;
        #pragma unroll
        for (int k = k0; k < k0 + 8; ++k)
            a = fmaf(t1s[k], ta_w2[k * 32 + o], a);
        part5[ks][o] = a;
    }
    __syncthreads();
    if (t < 32) {
        float a = 0.f;
        #pragma unroll
        for (int ks = 0; ks < 16; ++ks) a += part5[ks][t];
        t2s[t] = fmaxf(a + ta_b2[t], 0.f);
    }
    __syncthreads();

    // ---- stage 6: f1 = relu(t2 @ ff_w1 + b)  (32x64); 8 splits of 4
    {
        const int ks = t >> 6;
        const int o  = t & 63;
        float a = 0.f;
        const int k0 = ks * 4;
        #pragma unroll
        for (int k = k0; k < k0 + 4; ++k)
            a = fmaf(t2s[k], ff_w1[k * 64 + o], a);
        part6[ks][o] = a;
    }
    __syncthreads();
    if (t < 64) {
        float a = 0.f;
        #pragma unroll
        for (int ks = 0; ks < 8; ++ks) a += part6[ks][t];
        f1s[t] = fmaxf(a + ff_b1[t], 0.f);
    }
    __syncthreads();

    // ---- stage 7: f2 = relu(f1 @ ff_w2 + b)  (64x32); 16 splits of 4
    {
        const int ks = t >> 5;
        const int o  = t & 31;
        float a = 0.f;
        const int k0 = ks * 4;
        #pragma unroll
        for (int k = k0; k < k0 + 4; ++k)
            a = fmaf(f1s[k], ff_w2[k * 32 + o], a);
        part7[ks][o] = a;
    }
    __syncthreads();
    if (t < 32) {
        float a = 0.f;
        #pragma unroll
        for (int ks = 0; ks < 16; ++ks) a += part7[ks][t];
        f2s[t] = fmaxf(a + ff_b2[t], 0.f);
    }
    __syncthreads();

    // ---- stage 8: out = f2 @ ts_w + ts_b  (wave-0 shuffle reduce)
    if (t < 64) {
        float a = (t < 32) ? f2s[t] * ts_w[t] : 0.f;
        #pragma unroll
        for (int off = 16; off > 0; off >>= 1)
            a += __shfl_xor(a, off);
        if (t == 0) out[b] = a + ts_b[0];
    }
}

extern "C" void kernel_launch(void* const* d_in, const int* in_sizes, int n_in,
                              void* d_out, int out_size, void* d_ws, size_t ws_size,
                              hipStream_t stream) {
    const float* lstm    = (const float*)d_in[0];
    // d_in[1] first_notes: unused by reference
    const int*   trees   = (const int*)  d_in[2];
    // d_in[3] train: unused
    const float* emb     = (const float*)d_in[4];
    // d_in[5..8] att_*: DEAD in reference (del attn)
    const float* node_w1 = (const float*)d_in[9];
    const float* node_b1 = (const float*)d_in[10];
    const float* node_w2 = (const float*)d_in[11];
    const float* node_b2 = (const float*)d_in[12];
    const float* ta_w1   = (const float*)d_in[13];
    const float* ta_b1   = (const float*)d_in[14];
    const float* ta_w2   = (const float*)d_in[15];
    const float* ta_b2   = (const float*)d_in[16];
    const float* ff_w1   = (const float*)d_in[17];
    const float* ff_b1   = (const float*)d_in[18];
    const float* ff_w2   = (const float*)d_in[19];
    const float* ff_b2   = (const float*)d_in[20];
    const float* ts_w    = (const float*)d_in[21];
    const float* ts_b    = (const float*)d_in[22];
    float*       out     = (float*)d_out;

    disc_kernel<<<BATCH, 512, 0, stream>>>(
        lstm, trees, emb,
        node_w1, node_b1, node_w2, node_b2,
        ta_w1, ta_b1, ta_w2, ta_b2,
        ff_w1, ff_b1, ff_w2, ff_b2,
        ts_w, ts_b, out);
}